// Round 2
// baseline (426.146 us; speedup 1.0000x reference)
//
#include <hip/hip_runtime.h>
#include <hip/hip_bf16.h>

#define BATCH 32768
#define SEQ 512
#define NCH 8
#define CHL (SEQ / NCH)   // 64 timesteps per chunk
#define EPS 1e-8f

// Affine chunk-parallel scan: ret_t = a_t*ret_{t+1} + b_t with
//   a_t = gamma*(1-d_t)*lam_t,  b_t = r_t + gamma*(1-d_t)*(1-lam_t)*v_{t+1}
// Pass 1: per (row, chunk) compute segment composition (A,B): ret_s = A*ret_e + B
// Pass 2: fold downstream chunk summaries to get ret at chunk end, rescan chunk.

__global__ void __launch_bounds__(256)
glr_pass1(const float* __restrict__ values,
          const float* __restrict__ rewards,
          const float* __restrict__ dones,
          const float* __restrict__ raw_gamma,
          const float* __restrict__ raw_lambd,
          float2* __restrict__ ab) {          // [NCH][BATCH]
    __shared__ float s_lam[SEQ];
    for (int i = threadIdx.x; i < SEQ; i += blockDim.x)
        s_lam[i] = fmaxf(tanhf(raw_lambd[i]), EPS);
    __syncthreads();
    const float gamma = fmaxf(tanhf(raw_gamma[0]), EPS);

    const int gid = blockIdx.x * blockDim.x + threadIdx.x;
    const int row = gid & (BATCH - 1);
    const int c   = gid >> 15;                 // BATCH = 2^15; c uniform per block
    const float* __restrict__ vrow = values  + (size_t)row * (SEQ + 1);
    const float* __restrict__ rrow = rewards + (size_t)row * SEQ;
    const float* __restrict__ drow = dones   + (size_t)row * SEQ;

    const int s = c * CHL;
    float A = 1.f, Bv = 0.f;
    #pragma unroll 4
    for (int T = s + CHL - 4; T >= s; T -= 4) {
        const float4 r4 = *(const float4*)(rrow + T);
        const float4 d4 = *(const float4*)(drow + T);
        const float v1 = vrow[T + 1], v2 = vrow[T + 2];
        const float v3 = vrow[T + 3], v4 = vrow[T + 4];
        const float l0 = s_lam[T], l1 = s_lam[T + 1];
        const float l2 = s_lam[T + 2], l3 = s_lam[T + 3];

        float g, a, b;
        g = gamma * (1.f - d4.w); a = g * l3;
        b = fmaf(g * (1.f - l3), v4, r4.w);
        A = a * A; Bv = fmaf(a, Bv, b);

        g = gamma * (1.f - d4.z); a = g * l2;
        b = fmaf(g * (1.f - l2), v3, r4.z);
        A = a * A; Bv = fmaf(a, Bv, b);

        g = gamma * (1.f - d4.y); a = g * l1;
        b = fmaf(g * (1.f - l1), v2, r4.y);
        A = a * A; Bv = fmaf(a, Bv, b);

        g = gamma * (1.f - d4.x); a = g * l0;
        b = fmaf(g * (1.f - l0), v1, r4.x);
        A = a * A; Bv = fmaf(a, Bv, b);
    }
    ab[(size_t)c * BATCH + row] = make_float2(A, Bv);   // coalesced 8B stores
}

__global__ void __launch_bounds__(256)
glr_pass2(const float* __restrict__ values,
          const float* __restrict__ rewards,
          const float* __restrict__ dones,
          const float* __restrict__ raw_gamma,
          const float* __restrict__ raw_lambd,
          const float2* __restrict__ ab,
          float* __restrict__ out) {
    __shared__ float s_lam[SEQ];
    for (int i = threadIdx.x; i < SEQ; i += blockDim.x)
        s_lam[i] = fmaxf(tanhf(raw_lambd[i]), EPS);
    __syncthreads();
    const float gamma = fmaxf(tanhf(raw_gamma[0]), EPS);

    const int gid = blockIdx.x * blockDim.x + threadIdx.x;
    const int row = gid & (BATCH - 1);
    const int c   = gid >> 15;
    const float* __restrict__ vrow = values  + (size_t)row * (SEQ + 1);
    const float* __restrict__ rrow = rewards + (size_t)row * SEQ;
    const float* __restrict__ drow = dones   + (size_t)row * SEQ;
    float*       __restrict__ orow = out     + (size_t)row * SEQ;

    // ret at this chunk's right boundary: fold downstream summaries
    float ret = vrow[SEQ];
    for (int k = NCH - 1; k > c; --k) {       // uniform trip count per wave
        const float2 p = ab[(size_t)k * BATCH + row];
        ret = fmaf(p.x, ret, p.y);
    }

    const int s = c * CHL;
    #pragma unroll 4
    for (int T = s + CHL - 4; T >= s; T -= 4) {
        const float4 r4 = *(const float4*)(rrow + T);
        const float4 d4 = *(const float4*)(drow + T);
        const float v1 = vrow[T + 1], v2 = vrow[T + 2];
        const float v3 = vrow[T + 3], v4 = vrow[T + 4];
        const float l0 = s_lam[T], l1 = s_lam[T + 1];
        const float l2 = s_lam[T + 2], l3 = s_lam[T + 3];

        float boot;
        boot = (1.f - l3) * v4 + l3 * ret;
        ret = fmaf(gamma * (1.f - d4.w), boot, r4.w);
        const float o3 = ret;
        boot = (1.f - l2) * v3 + l2 * ret;
        ret = fmaf(gamma * (1.f - d4.z), boot, r4.z);
        const float o2 = ret;
        boot = (1.f - l1) * v2 + l1 * ret;
        ret = fmaf(gamma * (1.f - d4.y), boot, r4.y);
        const float o1 = ret;
        boot = (1.f - l0) * v1 + l0 * ret;
        ret = fmaf(gamma * (1.f - d4.x), boot, r4.x);
        const float o0 = ret;

        *(float4*)(orow + T) = make_float4(o0, o1, o2, o3);
    }
}

// Fallback (round-1 kernel) if ws is too small for chunk summaries.
__global__ void __launch_bounds__(64)
glr_serial(const float* __restrict__ values,
           const float* __restrict__ rewards,
           const float* __restrict__ dones,
           const float* __restrict__ raw_gamma,
           const float* __restrict__ raw_lambd,
           float* __restrict__ out) {
    __shared__ float s_lam[SEQ];
    for (int i = threadIdx.x; i < SEQ; i += blockDim.x)
        s_lam[i] = fmaxf(tanhf(raw_lambd[i]), EPS);
    __syncthreads();
    const float gamma = fmaxf(tanhf(raw_gamma[0]), EPS);
    const int b = blockIdx.x * blockDim.x + threadIdx.x;
    const float* __restrict__ vrow = values  + (size_t)b * (SEQ + 1);
    const float* __restrict__ rrow = rewards + (size_t)b * SEQ;
    const float* __restrict__ drow = dones   + (size_t)b * SEQ;
    float*       __restrict__ orow = out     + (size_t)b * SEQ;
    float ret = vrow[SEQ];
    #pragma unroll 4
    for (int T = SEQ - 4; T >= 0; T -= 4) {
        const float4 r4 = *(const float4*)(rrow + T);
        const float4 d4 = *(const float4*)(drow + T);
        const float v1 = vrow[T + 1], v2 = vrow[T + 2];
        const float v3 = vrow[T + 3], v4 = vrow[T + 4];
        const float l0 = s_lam[T], l1 = s_lam[T + 1];
        const float l2 = s_lam[T + 2], l3 = s_lam[T + 3];
        float boot;
        boot = (1.f - l3) * v4 + l3 * ret;
        ret = fmaf(gamma * (1.f - d4.w), boot, r4.w); const float o3 = ret;
        boot = (1.f - l2) * v3 + l2 * ret;
        ret = fmaf(gamma * (1.f - d4.z), boot, r4.z); const float o2 = ret;
        boot = (1.f - l1) * v2 + l1 * ret;
        ret = fmaf(gamma * (1.f - d4.y), boot, r4.y); const float o1 = ret;
        boot = (1.f - l0) * v1 + l0 * ret;
        ret = fmaf(gamma * (1.f - d4.x), boot, r4.x); const float o0 = ret;
        *(float4*)(orow + T) = make_float4(o0, o1, o2, o3);
    }
}

extern "C" void kernel_launch(void* const* d_in, const int* in_sizes, int n_in,
                              void* d_out, int out_size, void* d_ws, size_t ws_size,
                              hipStream_t stream) {
    const float* values    = (const float*)d_in[0];
    const float* rewards   = (const float*)d_in[1];
    const float* dones     = (const float*)d_in[2];
    const float* raw_gamma = (const float*)d_in[3];
    const float* raw_lambd = (const float*)d_in[4];
    float* out = (float*)d_out;

    const size_t ws_needed = (size_t)NCH * BATCH * sizeof(float2);  // 2 MB
    if (ws_size >= ws_needed) {
        float2* ab = (float2*)d_ws;
        const int block = 256;
        const int grid = BATCH * NCH / block;   // 1024 blocks
        glr_pass1<<<grid, block, 0, stream>>>(values, rewards, dones,
                                              raw_gamma, raw_lambd, ab);
        glr_pass2<<<grid, block, 0, stream>>>(values, rewards, dones,
                                              raw_gamma, raw_lambd, ab, out);
    } else {
        glr_serial<<<BATCH / 64, 64, 0, stream>>>(values, rewards, dones,
                                                  raw_gamma, raw_lambd, out);
    }
}

// Round 3
// 217.666 us; speedup vs baseline: 1.9578x; 1.9578x over previous
//
#include <hip/hip_runtime.h>
#include <hip/hip_bf16.h>

#define BATCH 32768
#define SEQ 512
#define TPL 8          // timesteps per lane (64 lanes * 8 = 512)
#define EPS 1e-8f

// One wave per row. Lane i owns t in [8i, 8i+8).
// Recurrence (reverse): ret_t = a_t * ret_{t+1} + b_t,
//   a_t = gamma*(1-d_t)*lam_t, b_t = r_t + gamma*(1-d_t)*(1-lam_t)*v_{t+1}.
// Affine maps compose associatively: per-lane segment summary, wave-level
// suffix scan via shuffles, then per-lane replay.
__global__ void __launch_bounds__(256)
glr_wave_scan(const float* __restrict__ values,
              const float* __restrict__ rewards,
              const float* __restrict__ dones,
              const float* __restrict__ raw_gamma,
              const float* __restrict__ raw_lambd,
              float* __restrict__ out) {
    __shared__ float s_lam[SEQ];
    for (int i = threadIdx.x; i < SEQ; i += 256)
        s_lam[i] = fmaxf(tanhf(raw_lambd[i]), EPS);
    __syncthreads();
    const float gamma = fmaxf(tanhf(raw_gamma[0]), EPS);

    const int lane = threadIdx.x & 63;
    const int wv   = threadIdx.x >> 6;
    const int row  = blockIdx.x * 4 + wv;

    const float* __restrict__ vrow = values  + (size_t)row * (SEQ + 1);
    const float* __restrict__ rrow = rewards + (size_t)row * SEQ;
    const float* __restrict__ drow = dones   + (size_t)row * SEQ;
    float*       __restrict__ orow = out     + (size_t)row * SEQ;

    const int t0 = lane * TPL;

    // ---- load this lane's 8 timesteps ----
    const float4 r4a = *(const float4*)(rrow + t0);
    const float4 r4b = *(const float4*)(rrow + t0 + 4);
    const float4 d4a = *(const float4*)(drow + t0);
    const float4 d4b = *(const float4*)(drow + t0 + 4);
    float rj[TPL] = {r4a.x, r4a.y, r4a.z, r4a.w, r4b.x, r4b.y, r4b.z, r4b.w};
    float dj[TPL] = {d4a.x, d4a.y, d4a.z, d4a.w, d4b.x, d4b.y, d4b.z, d4b.w};
    float vj[TPL];
    #pragma unroll
    for (int j = 0; j < TPL; ++j) vj[j] = vrow[t0 + j + 1];  // v_{t+1}
    float lm[TPL];
    #pragma unroll
    for (int j = 0; j < TPL; ++j) lm[j] = s_lam[t0 + j];

    // ---- per-lane affine summary (process t descending) ----
    float a[TPL], b[TPL];
    float A = 1.f, Bv = 0.f;
    #pragma unroll
    for (int j = TPL - 1; j >= 0; --j) {
        const float g = gamma * (1.f - dj[j]);
        a[j] = g * lm[j];
        b[j] = fmaf(g * (1.f - lm[j]), vj[j], rj[j]);
        Bv = fmaf(a[j], Bv, b[j]);
        A  = a[j] * A;
    }

    // ---- wave-level inclusive suffix scan of (A,B) ----
    #pragma unroll
    for (int dlt = 1; dlt < 64; dlt <<= 1) {
        const float oA = __shfl_down(A, dlt, 64);
        const float oB = __shfl_down(Bv, dlt, 64);
        if (lane + dlt < 64) {           // compose(mine, downstream)
            Bv = fmaf(A, oB, Bv);
            A  = A * oA;
        }
    }
    // exclusive: lane i needs suffix starting at lane i+1
    float EA = __shfl_down(A, 1, 64);
    float EB = __shfl_down(Bv, 1, 64);
    if (lane == 63) { EA = 1.f; EB = 0.f; }

    // ret at this lane's right boundary
    float ret = fmaf(EA, vrow[SEQ], EB);

    // ---- replay, emit outputs ----
    float o[TPL];
    #pragma unroll
    for (int j = TPL - 1; j >= 0; --j) {
        ret = fmaf(a[j], ret, b[j]);
        o[j] = ret;
    }
    *(float4*)(orow + t0)     = make_float4(o[0], o[1], o[2], o[3]);
    *(float4*)(orow + t0 + 4) = make_float4(o[4], o[5], o[6], o[7]);
}

extern "C" void kernel_launch(void* const* d_in, const int* in_sizes, int n_in,
                              void* d_out, int out_size, void* d_ws, size_t ws_size,
                              hipStream_t stream) {
    const float* values    = (const float*)d_in[0];
    const float* rewards   = (const float*)d_in[1];
    const float* dones     = (const float*)d_in[2];
    const float* raw_gamma = (const float*)d_in[3];
    const float* raw_lambd = (const float*)d_in[4];
    float* out = (float*)d_out;

    const int block = 256;                 // 4 waves = 4 rows per block
    const int grid = BATCH / 4;            // 8192 blocks
    glr_wave_scan<<<grid, block, 0, stream>>>(
        values, rewards, dones, raw_gamma, raw_lambd, out);
}

// Round 4
// 216.919 us; speedup vs baseline: 1.9645x; 1.0034x over previous
//
#include <hip/hip_runtime.h>
#include <hip/hip_bf16.h>

#define BATCH 32768
#define SEQ 512
#define TPL 8          // timesteps per lane (64 lanes * 8 = 512)
#define EPS 1e-8f
// Swizzled LDS index: +1 float pad per 8 -> stride-8 reads become 9*lane+j,
// gcd(9,32)=1 -> 2 lanes/bank across wave64 = conflict-free (m136).
#define SIG(k) ((k) + ((k) >> 3))
#define SWZ 576        // SIG(511)+1 = 574, round to 576

// One wave per row. Lane i owns t in [8i, 8i+8).
// ret_t = a_t*ret_{t+1} + b_t;  a_t = g*lam_t, b_t = r_t + g*(1-lam_t)*v_{t+1},
// g = gamma*(1-d_t). Per-lane affine summary -> 6-step wave suffix scan ->
// per-lane replay. values row (stride 513, misaligned) is staged via LDS with
// DENSE scalar loads so no wave instruction touches >5 cache lines.
__global__ void __launch_bounds__(256)
glr_wave_scan2(const float* __restrict__ values,
               const float* __restrict__ rewards,
               const float* __restrict__ dones,
               const float* __restrict__ raw_gamma,
               const float* __restrict__ raw_lambd,
               float* __restrict__ out) {
    __shared__ float s_lam[SWZ];
    __shared__ float s_v[4][SWZ];

    const int lane = threadIdx.x & 63;
    const int wv   = threadIdx.x >> 6;
    const int row  = blockIdx.x * 4 + wv;

    // ---- stage lambdas (block-wide, swizzled) ----
    for (int i = threadIdx.x; i < SEQ; i += 256)
        s_lam[SIG(i)] = fmaxf(tanhf(raw_lambd[i]), EPS);

    // ---- stage v_{t+1} = values[row][1..512] (per-wave, dense loads) ----
    const float* __restrict__ gv = values + (size_t)row * (SEQ + 1) + 1;
    #pragma unroll
    for (int j = 0; j < TPL; ++j) {
        const int k = 64 * j + lane;          // dense: lanes consecutive dwords
        s_v[wv][SIG(k)] = gv[k];
    }
    __syncthreads();

    const float gamma = fmaxf(tanhf(raw_gamma[0]), EPS);

    const float* __restrict__ rrow = rewards + (size_t)row * SEQ;
    const float* __restrict__ drow = dones   + (size_t)row * SEQ;
    float*       __restrict__ orow = out     + (size_t)row * SEQ;

    const int t0 = lane * TPL;

    // ---- load this lane's 8 timesteps (all dense / aligned) ----
    const float4 r4a = *(const float4*)(rrow + t0);
    const float4 r4b = *(const float4*)(rrow + t0 + 4);
    const float4 d4a = *(const float4*)(drow + t0);
    const float4 d4b = *(const float4*)(drow + t0 + 4);
    float rj[TPL] = {r4a.x, r4a.y, r4a.z, r4a.w, r4b.x, r4b.y, r4b.z, r4b.w};
    float dj[TPL] = {d4a.x, d4a.y, d4a.z, d4a.w, d4b.x, d4b.y, d4b.z, d4b.w};
    float vj[TPL], lm[TPL];
    #pragma unroll
    for (int j = 0; j < TPL; ++j) {
        vj[j] = s_v[wv][9 * lane + j];        // SIG(8*lane+j) = 9*lane+j
        lm[j] = s_lam[9 * lane + j];
    }

    // ---- per-lane affine summary (t descending) ----
    float a[TPL], b[TPL];
    float A = 1.f, Bv = 0.f;
    #pragma unroll
    for (int j = TPL - 1; j >= 0; --j) {
        const float g = gamma * (1.f - dj[j]);
        a[j] = g * lm[j];
        b[j] = fmaf(g * (1.f - lm[j]), vj[j], rj[j]);
        Bv = fmaf(a[j], Bv, b[j]);
        A  = a[j] * A;
    }

    // ---- wave-level inclusive suffix scan of (A,B) ----
    #pragma unroll
    for (int dlt = 1; dlt < 64; dlt <<= 1) {
        const float oA = __shfl_down(A, dlt, 64);
        const float oB = __shfl_down(Bv, dlt, 64);
        if (lane + dlt < 64) {                // compose(mine, downstream)
            Bv = fmaf(A, oB, Bv);
            A  = A * oA;
        }
    }
    // exclusive: lane i needs suffix starting at lane i+1
    float EA = __shfl_down(A, 1, 64);
    float EB = __shfl_down(Bv, 1, 64);
    if (lane == 63) { EA = 1.f; EB = 0.f; }

    // ret at this lane's right boundary; values[row][SEQ] == s_v[SEQ-1]
    const float vlast = s_v[wv][SIG(SEQ - 1)];   // broadcast read
    float ret = fmaf(EA, vlast, EB);

    // ---- replay, emit outputs ----
    float o[TPL];
    #pragma unroll
    for (int j = TPL - 1; j >= 0; --j) {
        ret = fmaf(a[j], ret, b[j]);
        o[j] = ret;
    }
    *(float4*)(orow + t0)     = make_float4(o[0], o[1], o[2], o[3]);
    *(float4*)(orow + t0 + 4) = make_float4(o[4], o[5], o[6], o[7]);
}

extern "C" void kernel_launch(void* const* d_in, const int* in_sizes, int n_in,
                              void* d_out, int out_size, void* d_ws, size_t ws_size,
                              hipStream_t stream) {
    const float* values    = (const float*)d_in[0];
    const float* rewards   = (const float*)d_in[1];
    const float* dones     = (const float*)d_in[2];
    const float* raw_gamma = (const float*)d_in[3];
    const float* raw_lambd = (const float*)d_in[4];
    float* out = (float*)d_out;

    const int block = 256;                 // 4 waves = 4 rows per block
    const int grid = BATCH / 4;            // 8192 blocks
    glr_wave_scan2<<<grid, block, 0, stream>>>(
        values, rewards, dones, raw_gamma, raw_lambd, out);
}